// Round 3
// baseline (783.364 us; speedup 1.0000x reference)
//
#include <hip/hip_runtime.h>
#include <math.h>

// Problem constants (fixed by the reference problem instance).
#define SDIM 64               // spike waveform length S
#define KCL  32               // num_clusters K
#define NPART (KCL*SDIM*2 + KCL)  // 4128 partials: sum[K*S] ++ sq[K*S] ++ cnt[K]
#define FACTOR_D 3.0          // second_match_factor
#define MAXDIST_TH 1280.0     // MAX_DIST * S = 20 * 64
#define MATCHED2_F 2.0f       // SPIKE_MATCHED_2

#define STATS_BLOCKS 512
#define STATS_THREADS 1024    // 16 waves/block, 2 blocks/CU -> full 32 waves/CU

// ---------------------------------------------------------------------------
// P1: per-cluster segment sums in f32 LDS (ds_add_f32, conflict-free banks).
// One row per wave per step; cluster ids pre-loaded 64 rows at a time so the
// inner loop has no load->branch->load latency chain. Blocks write their 4128
// f32 partials contiguously (coalesced) to pws[block][i]. No global atomics.
// Rows with cluster 0 are skipped: valid[0]=False so their stats are unused.
// ---------------------------------------------------------------------------
__global__ __launch_bounds__(STATS_THREADS) void stats_kernel(
    const float* __restrict__ spikes, const int* __restrict__ sortidx,
    float* __restrict__ pws, int n)
{
  __shared__ float part[NPART];
  for (int i = threadIdx.x; i < NPART; i += blockDim.x) part[i] = 0.0f;
  __syncthreads();

  float* s_sum = part;                 // [c*64 + s]
  float* s_sq  = part + KCL * SDIM;
  float* s_cnt = part + 2 * KCL * SDIM;

  const int wave = threadIdx.x >> 6;
  const int lane = threadIdx.x & 63;
  const int wpb  = blockDim.x >> 6;
  const int gw   = blockIdx.x * wpb + wave;
  const int nw   = gridDim.x * wpb;

  for (long long tb = (long long)gw * 64; tb < n; tb += (long long)nw * 64) {
    const long long rr = tb + lane;
    const int cv = (rr < n) ? sortidx[rr] : 0;   // 64 upcoming cluster ids

    if (tb + 64 <= n) {
#pragma unroll 8
      for (int j = 0; j < 64; ++j) {
        const int c = __shfl(cv, j, 64);         // wave-uniform
        if (c > 0 && c < KCL) {
          const float v = spikes[(size_t)(tb + j) * SDIM + lane];
          unsafeAtomicAdd(&s_sum[c * SDIM + lane], v);
          unsafeAtomicAdd(&s_sq[c * SDIM + lane], v * v);
        }
      }
    } else {
      const int jmax = (int)(n - tb);
      for (int j = 0; j < jmax; ++j) {
        const int c = __shfl(cv, j, 64);
        if (c > 0 && c < KCL) {
          const float v = spikes[(size_t)(tb + j) * SDIM + lane];
          unsafeAtomicAdd(&s_sum[c * SDIM + lane], v);
          unsafeAtomicAdd(&s_sq[c * SDIM + lane], v * v);
        }
      }
    }
    if (rr < n && cv > 0 && cv < KCL)
      unsafeAtomicAdd(&s_cnt[cv], 1.0f);         // one count per row
  }

  __syncthreads();
  for (int i = threadIdx.x; i < NPART; i += blockDim.x)
    pws[(size_t)blockIdx.x * NPART + i] = part[i];   // coalesced
}

// ---------------------------------------------------------------------------
// P2: deterministic tree reduce of block partials -> f64 gstats[4128].
// Block handles 64 units; wave w sums blocks b = w,w+4,...; coalesced reads.
// ---------------------------------------------------------------------------
__global__ __launch_bounds__(256) void reduce_kernel(
    const float* __restrict__ pws, double* __restrict__ gstats, int nb)
{
  __shared__ double s_acc[4][64];
  const int sub = threadIdx.x & 63;
  const int w   = threadIdx.x >> 6;
  const int u   = blockIdx.x * 64 + sub;
  double acc = 0.0;
  if (u < NPART)
    for (int b = w; b < nb; b += 4)
      acc += (double)pws[(size_t)b * NPART + u];
  s_acc[w][sub] = acc;
  __syncthreads();
  if (w == 0 && u < NPART)
    gstats[u] = ((s_acc[0][sub] + s_acc[1][sub]) +
                 (s_acc[2][sub] + s_acc[3][sub]));
}

// ---------------------------------------------------------------------------
// P3: finalize means (f32, transposed [s][c]), t2, thr = 3*std, valid (f64)
// ---------------------------------------------------------------------------
__global__ __launch_bounds__(256) void finalize_kernel(
    const double* __restrict__ gstats, float* __restrict__ meansTf,
    double* __restrict__ t2, double* __restrict__ thr, int* __restrict__ validk)
{
  __shared__ double s_var[KCL], s_t2[KCL];
  if (threadIdx.x < KCL) { s_var[threadIdx.x] = 0.0; s_t2[threadIdx.x] = 0.0; }
  __syncthreads();
  const double* gsum = gstats;
  const double* gsq  = gstats + KCL * SDIM;
  const double* gcnt = gstats + 2 * KCL * SDIM;
  for (int i = threadIdx.x; i < KCL * SDIM; i += blockDim.x) {
    const int c = i / SDIM, s = i % SDIM;
    const double cnt  = gcnt[c];
    const double safe = fmax(cnt, 1.0);
    const double m    = gsum[i] / safe;
    const double var  = gsq[i] / safe - m * m;
    meansTf[s * KCL + c] = (float)m;
    unsafeAtomicAdd(&s_var[c], var);
    unsafeAtomicAdd(&s_t2[c], m * m);
  }
  __syncthreads();
  if (threadIdx.x < KCL) {
    const int c = threadIdx.x;
    thr[c]    = FACTOR_D * sqrt(fmax(s_var[c], 0.0));
    t2[c]     = s_t2[c];
    validk[c] = (c != 0 && gcnt[c] > 0.0) ? 1 : 0;
  }
}

// ---------------------------------------------------------------------------
// P4: single output pass. Matched rows: pass-through stores. Unmatched rows
// (sort_idx==0): wave computes dist to all clusters (lane=cluster), threshold
// mask, first-index-tie argmin, MAX_DIST override. f32 dot loop; f64 combine/
// compares to preserve np ordering semantics.
// ---------------------------------------------------------------------------
__global__ __launch_bounds__(256) void assign_kernel(
    const float* __restrict__ spikes, const int* __restrict__ sortidx,
    const int* __restrict__ matchidx, const float* __restrict__ distance,
    const float* __restrict__ meansTf, const double* __restrict__ t2g,
    const double* __restrict__ thrg, const int* __restrict__ validk,
    float* __restrict__ out, int n)
{
  __shared__ float  s_mT[SDIM][KCL];   // [s][c]
  __shared__ double s_t2[KCL], s_thr[KCL];
  __shared__ int    s_valid[KCL];
  for (int i = threadIdx.x; i < SDIM * KCL; i += blockDim.x)
    (&s_mT[0][0])[i] = meansTf[i];
  if (threadIdx.x < KCL) {
    s_t2[threadIdx.x]    = t2g[threadIdx.x];
    s_thr[threadIdx.x]   = thrg[threadIdx.x];
    s_valid[threadIdx.x] = validk[threadIdx.x];
  }
  __syncthreads();

  const int wave = threadIdx.x >> 6;
  const int lane = threadIdx.x & 63;
  const int c    = lane & 31;
  const int gw   = blockIdx.x * (blockDim.x >> 6) + wave;
  const int nw   = gridDim.x * (blockDim.x >> 6);

  const bool   act = (lane < KCL) && (s_valid[c] != 0);
  const double tc  = s_t2[c];
  const double thc = s_thr[c];

  long long chunk = (((long long)n + nw - 1) / nw + 63) & ~63LL;
  const long long start = (long long)gw * chunk;
  long long end = start + chunk; if (end > n) end = n;

  for (long long rb = start; rb < end; rb += 64) {
    const long long rr = rb + lane;
    int cv = 1;
    if (rr < end) {
      cv = sortidx[rr];
      if (cv != 0) {                       // matched: pass-through
        out[rr]            = (float)cv;
        out[n + rr]        = (float)matchidx[rr];
        out[2LL * n + rr]  = distance[rr];
      }
    }
    unsigned long long mask = __ballot(rr < end && cv == 0);
    while (mask) {
      const int b = __ffsll(mask) - 1;
      mask &= mask - 1;
      const long long r = rb + b;

      const float xv = spikes[(size_t)r * SDIM + lane];
      float x2 = xv * xv;
#pragma unroll
      for (int off = 32; off > 0; off >>= 1) x2 += __shfl_xor(x2, off, 64);

      float dot = 0.0f;
#pragma unroll
      for (int s = 0; s < SDIM; ++s)
        dot = fmaf(__shfl(xv, s, 64), s_mT[s][c], dot);

      double dist; int idx = c;
      if (act) {
        const double d2 = (double)x2 - 2.0 * (double)dot + tc;
        dist = sqrt(fmax(d2, 1e-12));
        if (dist > thc) dist = (double)INFINITY;   // threshold mask
      } else {
        dist = (double)INFINITY;                   // invalid / duplicate lane
      }

#pragma unroll
      for (int off = 32; off > 0; off >>= 1) {     // min+argmin, first-idx tie
        const double od = __shfl_xor(dist, off, 64);
        const int    oi = __shfl_xor(idx, off, 64);
        if (od < dist || (od == dist && oi < idx)) { dist = od; idx = oi; }
      }

      if (lane == 0) {
        const int mz = (dist >= MAXDIST_TH) ? 0 : idx;
        out[r]            = (float)mz;
        out[n + r]        = MATCHED2_F;
        out[2LL * n + r]  = (float)dist;
      }
    }
  }
}

// ---------------------------------------------------------------------------
extern "C" void kernel_launch(void* const* d_in, const int* in_sizes, int n_in,
                              void* d_out, int out_size, void* d_ws, size_t ws_size,
                              hipStream_t stream) {
  const float* spikes   = (const float*)d_in[0];
  const int*   sortidx  = (const int*)d_in[1];
  const int*   matchidx = (const int*)d_in[2];
  const float* distance = (const float*)d_in[3];
  const int n = in_sizes[1];
  if (n <= 0) return;
  float* out = (float*)d_out;

  // ws layout: pws f32[STATS_BLOCKS*NPART] | gstats f64[NPART] | meansTf f32[2048]
  //            | t2 f64[32] | thr f64[32] | validk i32[32]   (~8.5 MB total)
  float*  pws     = (float*)d_ws;
  double* gstats  = (double*)((char*)d_ws + (size_t)STATS_BLOCKS * NPART * sizeof(float));
  float*  meansTf = (float*)(gstats + NPART);
  double* t2      = (double*)(meansTf + KCL * SDIM);
  double* thr     = t2 + KCL;
  int*    validk  = (int*)(thr + KCL);

  stats_kernel<<<STATS_BLOCKS, STATS_THREADS, 0, stream>>>(spikes, sortidx, pws, n);
  reduce_kernel<<<(NPART + 63) / 64, 256, 0, stream>>>(pws, gstats, STATS_BLOCKS);
  finalize_kernel<<<1, 256, 0, stream>>>(gstats, meansTf, t2, thr, validk);
  assign_kernel<<<1024, 256, 0, stream>>>(spikes, sortidx, matchidx, distance,
                                          meansTf, t2, thr, validk, out, n);
}

// Round 4
// 725.026 us; speedup vs baseline: 1.0805x; 1.0805x over previous
//
#include <hip/hip_runtime.h>
#include <math.h>

// Problem constants (fixed by the reference problem instance).
#define SDIM 64               // spike waveform length S
#define KCL  32               // num_clusters K
#define SPAD 65               // padded LDS row stride (words) to spread banks
#define NPART (KCL*SDIM*2 + KCL)  // 4128 partials: sum[K*S] ++ sq[K*S] ++ cnt[K]
#define FACTOR_D 3.0          // second_match_factor
#define MAXDIST_TH 1280.0     // MAX_DIST * S = 20 * 64
#define MATCHED2_F 2.0f       // SPIKE_MATCHED_2

#define STATS_BLOCKS 1024
#define STATS_THREADS 512     // 8 waves; 4 blocks/CU -> 32 waves/CU, LDS 4x33.5KB

// ---------------------------------------------------------------------------
// P1: per-cluster segment sums in padded f32 LDS. Wave = 4 rows x 16 lanes,
// float4 per lane (1 KB per wave load), 4x unrolled so ~4 KB of independent
// loads are in flight per wave. sortidx read per-lane (no shfl), spikes loaded
// UNCONDITIONALLY so the vector load never waits on the cluster test; only the
// LDS atomics are predicated. Rows with cluster 0 contribute nothing (their
// stats are unused: valid[0]=False). Partials flushed coalesced, no g-atomics.
// ---------------------------------------------------------------------------
__global__ __launch_bounds__(STATS_THREADS) void stats_kernel(
    const float* __restrict__ spikes, const int* __restrict__ sortidx,
    float* __restrict__ pws, int n)
{
  __shared__ float s_sum[KCL][SPAD];
  __shared__ float s_sq [KCL][SPAD];
  __shared__ float s_cnt[KCL];
  for (int i = threadIdx.x; i < KCL * SPAD; i += blockDim.x) {
    (&s_sum[0][0])[i] = 0.0f;
    (&s_sq[0][0])[i]  = 0.0f;
  }
  if (threadIdx.x < KCL) s_cnt[threadIdx.x] = 0.0f;
  __syncthreads();

  const int lane = threadIdx.x & 63;
  const int wave = threadIdx.x >> 6;
  const int rg   = lane >> 4;          // row within group of 4
  const int s0   = (lane & 15) * 4;    // float4 column offset
  const int gw   = blockIdx.x * (STATS_THREADS / 64) + wave;
  const int nw   = gridDim.x * (STATS_THREADS / 64);

  for (long long base = (long long)gw * 16; base < n;
       base += (long long)nw * 16) {
#pragma unroll
    for (int ii = 0; ii < 4; ++ii) {
      const long long row = base + ii * 4 + rg;
      int c = 0;
      float4 v = make_float4(0.f, 0.f, 0.f, 0.f);
      if (row < n) {
        c = sortidx[row];                                    // per-lane, no shfl
        v = *reinterpret_cast<const float4*>(
            spikes + (size_t)row * SDIM + s0);               // unconditional
      }
      if (c > 0 && c < KCL) {
        unsafeAtomicAdd(&s_sum[c][s0 + 0], v.x);
        unsafeAtomicAdd(&s_sum[c][s0 + 1], v.y);
        unsafeAtomicAdd(&s_sum[c][s0 + 2], v.z);
        unsafeAtomicAdd(&s_sum[c][s0 + 3], v.w);
        unsafeAtomicAdd(&s_sq[c][s0 + 0], v.x * v.x);
        unsafeAtomicAdd(&s_sq[c][s0 + 1], v.y * v.y);
        unsafeAtomicAdd(&s_sq[c][s0 + 2], v.z * v.z);
        unsafeAtomicAdd(&s_sq[c][s0 + 3], v.w * v.w);
        if (s0 == 0) unsafeAtomicAdd(&s_cnt[c], 1.0f);       // one per row
      }
    }
  }

  __syncthreads();
  for (int i = threadIdx.x; i < KCL * SDIM; i += blockDim.x) {
    pws[(size_t)blockIdx.x * NPART + i]              = s_sum[i >> 6][i & 63];
    pws[(size_t)blockIdx.x * NPART + KCL * SDIM + i] = s_sq[i >> 6][i & 63];
  }
  if (threadIdx.x < KCL)
    pws[(size_t)blockIdx.x * NPART + 2 * KCL * SDIM + threadIdx.x] =
        s_cnt[threadIdx.x];
}

// ---------------------------------------------------------------------------
// P2: deterministic tree reduce of block partials -> f64 gstats[4128].
// Block handles 64 consecutive units; wave w sums partial-blocks b=w,w+16,...
// (coalesced 256B reads), then a fixed-order cross-wave sum. Deterministic.
// ---------------------------------------------------------------------------
__global__ __launch_bounds__(1024) void reduce_kernel(
    const float* __restrict__ pws, double* __restrict__ gstats, int nb)
{
  __shared__ double s_acc[16][64];
  const int sub = threadIdx.x & 63;
  const int w   = threadIdx.x >> 6;
  const int u   = blockIdx.x * 64 + sub;
  double acc = 0.0;
  if (u < NPART)
    for (int b = w; b < nb; b += 16)
      acc += (double)pws[(size_t)b * NPART + u];
  s_acc[w][sub] = acc;
  __syncthreads();
  if (w == 0 && u < NPART) {
    double t = 0.0;
#pragma unroll
    for (int j = 0; j < 16; ++j) t += s_acc[j][sub];
    gstats[u] = t;
  }
}

// ---------------------------------------------------------------------------
// P3: finalize means (f32, transposed [s][c]), t2, thr = 3*std, valid (f64)
// ---------------------------------------------------------------------------
__global__ __launch_bounds__(256) void finalize_kernel(
    const double* __restrict__ gstats, float* __restrict__ meansTf,
    double* __restrict__ t2, double* __restrict__ thr, int* __restrict__ validk)
{
  __shared__ double s_var[KCL], s_t2[KCL];
  if (threadIdx.x < KCL) { s_var[threadIdx.x] = 0.0; s_t2[threadIdx.x] = 0.0; }
  __syncthreads();
  const double* gsum = gstats;
  const double* gsq  = gstats + KCL * SDIM;
  const double* gcnt = gstats + 2 * KCL * SDIM;
  for (int i = threadIdx.x; i < KCL * SDIM; i += blockDim.x) {
    const int c = i / SDIM, s = i % SDIM;
    const double cnt  = gcnt[c];
    const double safe = fmax(cnt, 1.0);
    const double m    = gsum[i] / safe;
    const double var  = gsq[i] / safe - m * m;
    meansTf[s * KCL + c] = (float)m;
    unsafeAtomicAdd(&s_var[c], var);
    unsafeAtomicAdd(&s_t2[c], m * m);
  }
  __syncthreads();
  if (threadIdx.x < KCL) {
    const int c = threadIdx.x;
    thr[c]    = FACTOR_D * sqrt(fmax(s_var[c], 0.0));
    t2[c]     = s_t2[c];
    validk[c] = (c != 0 && gcnt[c] > 0.0) ? 1 : 0;
  }
}

// ---------------------------------------------------------------------------
// P4: single output pass. Matched rows: pass-through stores. Unmatched rows
// (sort_idx==0): wave computes dist to all clusters (lane=cluster), threshold
// mask, first-index-tie argmin, MAX_DIST override. f32 dot loop; f64 combine/
// compares to preserve np ordering semantics.
// ---------------------------------------------------------------------------
__global__ __launch_bounds__(256) void assign_kernel(
    const float* __restrict__ spikes, const int* __restrict__ sortidx,
    const int* __restrict__ matchidx, const float* __restrict__ distance,
    const float* __restrict__ meansTf, const double* __restrict__ t2g,
    const double* __restrict__ thrg, const int* __restrict__ validk,
    float* __restrict__ out, int n)
{
  __shared__ float  s_mT[SDIM][KCL];   // [s][c]
  __shared__ double s_t2[KCL], s_thr[KCL];
  __shared__ int    s_valid[KCL];
  for (int i = threadIdx.x; i < SDIM * KCL; i += blockDim.x)
    (&s_mT[0][0])[i] = meansTf[i];
  if (threadIdx.x < KCL) {
    s_t2[threadIdx.x]    = t2g[threadIdx.x];
    s_thr[threadIdx.x]   = thrg[threadIdx.x];
    s_valid[threadIdx.x] = validk[threadIdx.x];
  }
  __syncthreads();

  const int wave = threadIdx.x >> 6;
  const int lane = threadIdx.x & 63;
  const int c    = lane & 31;
  const int gw   = blockIdx.x * (blockDim.x >> 6) + wave;
  const int nw   = gridDim.x * (blockDim.x >> 6);

  const bool   act = (lane < KCL) && (s_valid[c] != 0);
  const double tc  = s_t2[c];
  const double thc = s_thr[c];

  long long chunk = (((long long)n + nw - 1) / nw + 63) & ~63LL;
  const long long start = (long long)gw * chunk;
  long long end = start + chunk; if (end > n) end = n;

  for (long long rb = start; rb < end; rb += 64) {
    const long long rr = rb + lane;
    int cv = 1;
    if (rr < end) {
      cv = sortidx[rr];
      if (cv != 0) {                       // matched: pass-through
        out[rr]            = (float)cv;
        out[n + rr]        = (float)matchidx[rr];
        out[2LL * n + rr]  = distance[rr];
      }
    }
    unsigned long long mask = __ballot(rr < end && cv == 0);
    while (mask) {
      const int b = __ffsll(mask) - 1;
      mask &= mask - 1;
      const long long r = rb + b;

      const float xv = spikes[(size_t)r * SDIM + lane];
      float x2 = xv * xv;
#pragma unroll
      for (int off = 32; off > 0; off >>= 1) x2 += __shfl_xor(x2, off, 64);

      float dot = 0.0f;
#pragma unroll
      for (int s = 0; s < SDIM; ++s)
        dot = fmaf(__shfl(xv, s, 64), s_mT[s][c], dot);

      double dist; int idx = c;
      if (act) {
        const double d2 = (double)x2 - 2.0 * (double)dot + tc;
        dist = sqrt(fmax(d2, 1e-12));
        if (dist > thc) dist = (double)INFINITY;   // threshold mask
      } else {
        dist = (double)INFINITY;                   // invalid / duplicate lane
      }

#pragma unroll
      for (int off = 32; off > 0; off >>= 1) {     // min+argmin, first-idx tie
        const double od = __shfl_xor(dist, off, 64);
        const int    oi = __shfl_xor(idx, off, 64);
        if (od < dist || (od == dist && oi < idx)) { dist = od; idx = oi; }
      }

      if (lane == 0) {
        const int mz = (dist >= MAXDIST_TH) ? 0 : idx;
        out[r]            = (float)mz;
        out[n + r]        = MATCHED2_F;
        out[2LL * n + r]  = (float)dist;
      }
    }
  }
}

// ---------------------------------------------------------------------------
extern "C" void kernel_launch(void* const* d_in, const int* in_sizes, int n_in,
                              void* d_out, int out_size, void* d_ws, size_t ws_size,
                              hipStream_t stream) {
  const float* spikes   = (const float*)d_in[0];
  const int*   sortidx  = (const int*)d_in[1];
  const int*   matchidx = (const int*)d_in[2];
  const float* distance = (const float*)d_in[3];
  const int n = in_sizes[1];
  if (n <= 0) return;
  float* out = (float*)d_out;

  // ws layout: pws f32[STATS_BLOCKS*NPART] (~16.9 MB) | gstats f64[NPART]
  //            | meansTf f32[2048] | t2 f64[32] | thr f64[32] | validk i32[32]
  float*  pws     = (float*)d_ws;
  double* gstats  = (double*)((char*)d_ws + (size_t)STATS_BLOCKS * NPART * sizeof(float));
  float*  meansTf = (float*)(gstats + NPART);
  double* t2      = (double*)(meansTf + KCL * SDIM);
  double* thr     = t2 + KCL;
  int*    validk  = (int*)(thr + KCL);

  stats_kernel<<<STATS_BLOCKS, STATS_THREADS, 0, stream>>>(spikes, sortidx, pws, n);
  reduce_kernel<<<(NPART + 63) / 64, 1024, 0, stream>>>(pws, gstats, STATS_BLOCKS);
  finalize_kernel<<<1, 256, 0, stream>>>(gstats, meansTf, t2, thr, validk);
  assign_kernel<<<2048, 256, 0, stream>>>(spikes, sortidx, matchidx, distance,
                                          meansTf, t2, thr, validk, out, n);
}

// Round 5
// 186.760 us; speedup vs baseline: 4.1945x; 3.8821x over previous
//
#include <hip/hip_runtime.h>
#include <math.h>

// Problem constants (fixed by the reference problem instance).
#define SDIM 64               // spike waveform length S
#define KCL  32               // num_clusters K
#define NPART (KCL*SDIM*2 + KCL)  // 4128 f64 partials: sum[K*S] ++ sq[K*S] ++ cnt[K]
#define FACTOR_D 3.0          // second_match_factor
#define MAXDIST_TH 1280.0     // MAX_DIST * S = 20 * 64
#define MATCHED2_F 2.0f       // SPIKE_MATCHED_2

#define SB 1024               // stats grid (4 blocks/CU)
#define ST 512                // stats threads = 8 waves
#define BATCH 128             // rows staged per batch (32 KB LDS)

// ---------------------------------------------------------------------------
// P1: owner-computes segment sums, ZERO atomics.
// Per batch: block stages 128 contiguous rows into LDS (float4 reg-staging,
// loads issued before the barrier so HBM latency hides under the previous
// batch's processing). Wave w owns clusters [4w, 4w+4): it ballots the 128
// staged cluster ids, and for each matching row adds the row (64 lanes = 64
// columns) into per-lane f64 REGISTER accumulators. Static 4-way branch on
// the wave-uniform accumulator index (no runtime-indexed arrays -> no
// scratch). Each staged row is ds_read exactly once, 2-way bank = free.
// Partials flushed coalesced as f64; no global atomics.
// ---------------------------------------------------------------------------
__global__ __launch_bounds__(ST) void stats_kernel(
    const float* __restrict__ spikes, const int* __restrict__ sortidx,
    double* __restrict__ pws, int n)
{
  __shared__ float rows[BATCH * SDIM];   // 32 KB, linear [row][col]
  const int lane = threadIdx.x & 63;
  const int w    = threadIdx.x >> 6;     // wave 0..7
  const int c0   = w * 4;                // first owned cluster

  double sum0=0,sum1=0,sum2=0,sum3=0;
  double sq0 =0,sq1 =0,sq2 =0,sq3 =0;
  double cn0 =0,cn1 =0,cn2 =0,cn3 =0;

  const int nbatch = (n + BATCH - 1) / BATCH;
  const size_t gmax = (size_t)n * SDIM * sizeof(float) - 16;

  for (int bi = blockIdx.x; bi < nbatch; bi += gridDim.x) {
    const long long r0   = (long long)bi * BATCH;
    const size_t    gbase = (size_t)r0 * SDIM * sizeof(float);

    // issue this batch's global loads BEFORE the barrier (overlap w/ compute)
    float4 v0, v1, v2, v3;
    {
      size_t g0 = gbase + (size_t)threadIdx.x * 16;
      size_t g1 = g0 + 8192, g2 = g0 + 16384, g3 = g0 + 24576;
      if (g0 > gmax) g0 = gmax;
      if (g1 > gmax) g1 = gmax;
      if (g2 > gmax) g2 = gmax;
      if (g3 > gmax) g3 = gmax;
      v0 = *reinterpret_cast<const float4*>((const char*)spikes + g0);
      v1 = *reinterpret_cast<const float4*>((const char*)spikes + g1);
      v2 = *reinterpret_cast<const float4*>((const char*)spikes + g2);
      v3 = *reinterpret_cast<const float4*>((const char*)spikes + g3);
    }
    const long long ra = r0 + lane, rb = r0 + 64 + lane;
    const int cva = (ra < n) ? sortidx[ra] : -1;   // ids for rows 0..63
    const int cvb = (rb < n) ? sortidx[rb] : -1;   // ids for rows 64..127

    __syncthreads();   // previous batch fully consumed
    {
      char* lb = (char*)rows + (size_t)threadIdx.x * 16;
      *reinterpret_cast<float4*>(lb)         = v0;
      *reinterpret_cast<float4*>(lb + 8192)  = v1;
      *reinterpret_cast<float4*>(lb + 16384) = v2;
      *reinterpret_cast<float4*>(lb + 24576) = v3;
    }
    __syncthreads();   // batch staged

    unsigned long long m0 = __ballot(cva >= c0 && cva < c0 + 4);
    unsigned long long m1 = __ballot(cvb >= c0 && cvb < c0 + 4);
    while (m0) {
      const int b = __ffsll(m0) - 1; m0 &= m0 - 1;
      const int cb = __shfl(cva, b, 64);           // wave-uniform cluster id
      const double dv = (double)rows[b * SDIM + lane];
      const int j = cb - c0;
      if      (j == 0) { sum0 += dv; sq0 = fma(dv, dv, sq0); cn0 += 1.0; }
      else if (j == 1) { sum1 += dv; sq1 = fma(dv, dv, sq1); cn1 += 1.0; }
      else if (j == 2) { sum2 += dv; sq2 = fma(dv, dv, sq2); cn2 += 1.0; }
      else             { sum3 += dv; sq3 = fma(dv, dv, sq3); cn3 += 1.0; }
    }
    while (m1) {
      const int b = __ffsll(m1) - 1; m1 &= m1 - 1;
      const int cb = __shfl(cvb, b, 64);
      const double dv = (double)rows[(64 + b) * SDIM + lane];
      const int j = cb - c0;
      if      (j == 0) { sum0 += dv; sq0 = fma(dv, dv, sq0); cn0 += 1.0; }
      else if (j == 1) { sum1 += dv; sq1 = fma(dv, dv, sq1); cn1 += 1.0; }
      else if (j == 2) { sum2 += dv; sq2 = fma(dv, dv, sq2); cn2 += 1.0; }
      else             { sum3 += dv; sq3 = fma(dv, dv, sq3); cn3 += 1.0; }
    }
  }

  // flush per-block f64 partials, coalesced (512 B per wave-store)
  double* pb = pws + (size_t)blockIdx.x * NPART;
  pb[(c0 + 0) * SDIM + lane] = sum0;
  pb[(c0 + 1) * SDIM + lane] = sum1;
  pb[(c0 + 2) * SDIM + lane] = sum2;
  pb[(c0 + 3) * SDIM + lane] = sum3;
  pb[KCL * SDIM + (c0 + 0) * SDIM + lane] = sq0;
  pb[KCL * SDIM + (c0 + 1) * SDIM + lane] = sq1;
  pb[KCL * SDIM + (c0 + 2) * SDIM + lane] = sq2;
  pb[KCL * SDIM + (c0 + 3) * SDIM + lane] = sq3;
  if (lane == 0) {                      // every lane holds the true count
    pb[2 * KCL * SDIM + c0 + 0] = cn0;
    pb[2 * KCL * SDIM + c0 + 1] = cn1;
    pb[2 * KCL * SDIM + c0 + 2] = cn2;
    pb[2 * KCL * SDIM + c0 + 3] = cn3;
  }
}

// ---------------------------------------------------------------------------
// P2: deterministic f64 tree reduce of block partials -> gstats[4128].
// Block handles 64 contiguous units; wave w sums blocks b=w,w+16,... with
// fully-coalesced 512 B reads; fixed-order cross-wave combine.
// ---------------------------------------------------------------------------
__global__ __launch_bounds__(1024) void reduce_kernel(
    const double* __restrict__ pws, double* __restrict__ gstats, int nb)
{
  __shared__ double s_acc[16][64];
  const int lane = threadIdx.x & 63;
  const int w    = threadIdx.x >> 6;
  const int u    = blockIdx.x * 64 + lane;
  double acc = 0.0;
  if (u < NPART)
    for (int b = w; b < nb; b += 16)
      acc += pws[(size_t)b * NPART + u];
  s_acc[w][lane] = acc;
  __syncthreads();
  if (w == 0 && u < NPART) {
    double t = 0.0;
#pragma unroll
    for (int j = 0; j < 16; ++j) t += s_acc[j][lane];
    gstats[u] = t;
  }
}

// ---------------------------------------------------------------------------
// P3: finalize means (f32, transposed [s][c]), t2, thr = 3*std, valid (f64)
// ---------------------------------------------------------------------------
__global__ __launch_bounds__(256) void finalize_kernel(
    const double* __restrict__ gstats, float* __restrict__ meansTf,
    double* __restrict__ t2, double* __restrict__ thr, int* __restrict__ validk)
{
  __shared__ double s_var[KCL], s_t2[KCL];
  if (threadIdx.x < KCL) { s_var[threadIdx.x] = 0.0; s_t2[threadIdx.x] = 0.0; }
  __syncthreads();
  const double* gsum = gstats;
  const double* gsq  = gstats + KCL * SDIM;
  const double* gcnt = gstats + 2 * KCL * SDIM;
  for (int i = threadIdx.x; i < KCL * SDIM; i += blockDim.x) {
    const int c = i / SDIM, s = i % SDIM;
    const double cnt  = gcnt[c];
    const double safe = fmax(cnt, 1.0);
    const double m    = gsum[i] / safe;
    const double var  = gsq[i] / safe - m * m;
    meansTf[s * KCL + c] = (float)m;
    unsafeAtomicAdd(&s_var[c], var);
    unsafeAtomicAdd(&s_t2[c], m * m);
  }
  __syncthreads();
  if (threadIdx.x < KCL) {
    const int c = threadIdx.x;
    thr[c]    = FACTOR_D * sqrt(fmax(s_var[c], 0.0));
    t2[c]     = s_t2[c];
    validk[c] = (c != 0 && gcnt[c] > 0.0) ? 1 : 0;
  }
}

// ---------------------------------------------------------------------------
// P4: single output pass. Matched rows: pass-through stores. Unmatched rows
// (sort_idx==0): wave computes dist to all clusters (lane=cluster), threshold
// mask, first-index-tie argmin, MAX_DIST override. f32 dot loop; f64 combine/
// compares to preserve np ordering semantics.
// ---------------------------------------------------------------------------
__global__ __launch_bounds__(256) void assign_kernel(
    const float* __restrict__ spikes, const int* __restrict__ sortidx,
    const int* __restrict__ matchidx, const float* __restrict__ distance,
    const float* __restrict__ meansTf, const double* __restrict__ t2g,
    const double* __restrict__ thrg, const int* __restrict__ validk,
    float* __restrict__ out, int n)
{
  __shared__ float  s_mT[SDIM][KCL];   // [s][c]
  __shared__ double s_t2[KCL], s_thr[KCL];
  __shared__ int    s_valid[KCL];
  for (int i = threadIdx.x; i < SDIM * KCL; i += blockDim.x)
    (&s_mT[0][0])[i] = meansTf[i];
  if (threadIdx.x < KCL) {
    s_t2[threadIdx.x]    = t2g[threadIdx.x];
    s_thr[threadIdx.x]   = thrg[threadIdx.x];
    s_valid[threadIdx.x] = validk[threadIdx.x];
  }
  __syncthreads();

  const int wave = threadIdx.x >> 6;
  const int lane = threadIdx.x & 63;
  const int c    = lane & 31;
  const int gw   = blockIdx.x * (blockDim.x >> 6) + wave;
  const int nw   = gridDim.x * (blockDim.x >> 6);

  const bool   act = (lane < KCL) && (s_valid[c] != 0);
  const double tc  = s_t2[c];
  const double thc = s_thr[c];

  long long chunk = (((long long)n + nw - 1) / nw + 63) & ~63LL;
  const long long start = (long long)gw * chunk;
  long long end = start + chunk; if (end > n) end = n;

  for (long long rbase = start; rbase < end; rbase += 64) {
    const long long rr = rbase + lane;
    int cv = 1;
    if (rr < end) {
      cv = sortidx[rr];
      if (cv != 0) {                       // matched: pass-through
        out[rr]            = (float)cv;
        out[n + rr]        = (float)matchidx[rr];
        out[2LL * n + rr]  = distance[rr];
      }
    }
    unsigned long long mask = __ballot(rr < end && cv == 0);
    while (mask) {
      const int b = __ffsll(mask) - 1;
      mask &= mask - 1;
      const long long r = rbase + b;

      const float xv = spikes[(size_t)r * SDIM + lane];
      float x2 = xv * xv;
#pragma unroll
      for (int off = 32; off > 0; off >>= 1) x2 += __shfl_xor(x2, off, 64);

      float dot = 0.0f;
#pragma unroll
      for (int s = 0; s < SDIM; ++s)
        dot = fmaf(__shfl(xv, s, 64), s_mT[s][c], dot);

      double dist; int idx = c;
      if (act) {
        const double d2 = (double)x2 - 2.0 * (double)dot + tc;
        dist = sqrt(fmax(d2, 1e-12));
        if (dist > thc) dist = (double)INFINITY;   // threshold mask
      } else {
        dist = (double)INFINITY;                   // invalid / duplicate lane
      }

#pragma unroll
      for (int off = 32; off > 0; off >>= 1) {     // min+argmin, first-idx tie
        const double od = __shfl_xor(dist, off, 64);
        const int    oi = __shfl_xor(idx, off, 64);
        if (od < dist || (od == dist && oi < idx)) { dist = od; idx = oi; }
      }

      if (lane == 0) {
        const int mz = (dist >= MAXDIST_TH) ? 0 : idx;
        out[r]            = (float)mz;
        out[n + r]        = MATCHED2_F;
        out[2LL * n + r]  = (float)dist;
      }
    }
  }
}

// ---------------------------------------------------------------------------
extern "C" void kernel_launch(void* const* d_in, const int* in_sizes, int n_in,
                              void* d_out, int out_size, void* d_ws, size_t ws_size,
                              hipStream_t stream) {
  const float* spikes   = (const float*)d_in[0];
  const int*   sortidx  = (const int*)d_in[1];
  const int*   matchidx = (const int*)d_in[2];
  const float* distance = (const float*)d_in[3];
  const int n = in_sizes[1];
  if (n <= 0) return;
  float* out = (float*)d_out;

  // ws layout: pws f64[SB*NPART] (~33.8 MB) | gstats f64[NPART]
  //            | meansTf f32[2048] | t2 f64[32] | thr f64[32] | validk i32[32]
  double* pws     = (double*)d_ws;
  double* gstats  = pws + (size_t)SB * NPART;
  float*  meansTf = (float*)(gstats + NPART);
  double* t2      = (double*)(meansTf + KCL * SDIM);
  double* thr     = t2 + KCL;
  int*    validk  = (int*)(thr + KCL);

  stats_kernel<<<SB, ST, 0, stream>>>(spikes, sortidx, pws, n);
  reduce_kernel<<<(NPART + 63) / 64, 1024, 0, stream>>>(pws, gstats, SB);
  finalize_kernel<<<1, 256, 0, stream>>>(gstats, meansTf, t2, thr, validk);
  assign_kernel<<<2048, 256, 0, stream>>>(spikes, sortidx, matchidx, distance,
                                          meansTf, t2, thr, validk, out, n);
}

// Round 6
// 142.021 us; speedup vs baseline: 5.5158x; 1.3150x over previous
//
#include <hip/hip_runtime.h>
#include <math.h>

// Problem constants (fixed by the reference problem instance).
#define SDIM 64               // spike waveform length S
#define KCL  32               // num_clusters K
#define NPART (KCL*SDIM*2 + KCL)  // 4128 partials: sum[K*S] ++ sq[K*S] ++ cnt[K]
#define FACTOR_D 3.0          // second_match_factor
#define MAXDIST_TH 1280.0     // MAX_DIST * S = 20 * 64
#define MATCHED2_F 2.0f       // SPIKE_MATCHED_2

#define SB 1024               // stats grid (4 blocks/CU)
#define ST 512                // stats threads = 8 waves
#define BATCH 128             // rows staged per batch (32 KB LDS)

// ---------------------------------------------------------------------------
// P1: owner-computes segment sums, zero atomics, latency-optimized.
// Wave w owns clusters 4w..4w+3. Per batch: ballot one 64-bit mask per owned
// cluster (no per-row shfl/branch), then pop 4 masks TOGETHER per iteration:
// 4 independent ds_reads in flight, predicated f32 accumulate. Next batch's
// global loads are issued before the accumulate phase (T14: HBM latency hides
// under compute). f32 register accumulators; f32 partials (precision verified
// in R3/R4: absmax 0.0). Cluster 0 skipped (stats unused, valid[0]=False).
// ---------------------------------------------------------------------------
__global__ __launch_bounds__(ST) void stats_kernel(
    const float* __restrict__ spikes, const int* __restrict__ sortidx,
    float* __restrict__ pws, int n)
{
  __shared__ float rows[BATCH * SDIM];   // 32 KB, linear [row][col]
  const int lane  = threadIdx.x & 63;
  const int w     = threadIdx.x >> 6;    // wave 0..7
  const int cbase = w * 4;               // first owned cluster

  float s0=0,s1=0,s2=0,s3=0;             // per-lane column sums, 4 clusters
  float q0=0,q1=0,q2=0,q3=0;             // column sums of squares
  float cn0=0,cn1=0,cn2=0,cn3=0;         // row counts (wave-uniform)

  const long long nbatch = ((long long)n + BATCH - 1) / BATCH;
  const size_t gmax = (size_t)n * SDIM * sizeof(float) - 16;

  float4 v0, v1, v2, v3;                 // staged-batch registers
  int ida, idb;                          // cluster ids rows 0..63 / 64..127

#define LOADBATCH(B)                                                         \
  {                                                                          \
    const long long bsafe = ((B) < nbatch) ? (B) : 0;                        \
    size_t g0 = (size_t)bsafe * BATCH * SDIM * sizeof(float) +               \
                (size_t)threadIdx.x * 16;                                    \
    size_t g1 = g0 + 8192, g2 = g0 + 16384, g3 = g0 + 24576;                 \
    if (g0 > gmax) g0 = gmax;                                                \
    if (g1 > gmax) g1 = gmax;                                                \
    if (g2 > gmax) g2 = gmax;                                                \
    if (g3 > gmax) g3 = gmax;                                                \
    v0 = *reinterpret_cast<const float4*>((const char*)spikes + g0);         \
    v1 = *reinterpret_cast<const float4*>((const char*)spikes + g1);         \
    v2 = *reinterpret_cast<const float4*>((const char*)spikes + g2);         \
    v3 = *reinterpret_cast<const float4*>((const char*)spikes + g3);         \
    const long long ra = bsafe * BATCH + lane, rb = ra + 64;                 \
    ida = ((B) < nbatch && ra < n) ? sortidx[ra] : -1;                       \
    idb = ((B) < nbatch && rb < n) ? sortidx[rb] : -1;                       \
  }

#define POPLOOP(m0,m1,m2,m3,BASE)                                            \
  while (m0 | m1 | m2 | m3) {                                                \
    const bool e0 = m0 != 0, e1 = m1 != 0, e2 = m2 != 0, e3 = m3 != 0;       \
    const int b0 = e0 ? __ffsll(m0) - 1 : 0;                                 \
    const int b1 = e1 ? __ffsll(m1) - 1 : 0;                                 \
    const int b2 = e2 ? __ffsll(m2) - 1 : 0;                                 \
    const int b3 = e3 ? __ffsll(m3) - 1 : 0;                                 \
    m0 &= m0 - 1; m1 &= m1 - 1; m2 &= m2 - 1; m3 &= m3 - 1;                  \
    const float x0 = rows[((BASE) + b0) * SDIM + lane];                      \
    const float x1 = rows[((BASE) + b1) * SDIM + lane];                      \
    const float x2 = rows[((BASE) + b2) * SDIM + lane];                      \
    const float x3 = rows[((BASE) + b3) * SDIM + lane];                      \
    const float y0 = e0 ? x0 : 0.0f, y1 = e1 ? x1 : 0.0f;                    \
    const float y2 = e2 ? x2 : 0.0f, y3 = e3 ? x3 : 0.0f;                    \
    s0 += y0; q0 = fmaf(y0, x0, q0); cn0 += e0 ? 1.0f : 0.0f;                \
    s1 += y1; q1 = fmaf(y1, x1, q1); cn1 += e1 ? 1.0f : 0.0f;                \
    s2 += y2; q2 = fmaf(y2, x2, q2); cn2 += e2 ? 1.0f : 0.0f;                \
    s3 += y3; q3 = fmaf(y3, x3, q3); cn3 += e3 ? 1.0f : 0.0f;                \
  }

  long long bi = blockIdx.x;
  LOADBATCH(bi);                         // prologue

  for (; bi < nbatch; bi += gridDim.x) {
    __syncthreads();                     // previous batch fully consumed
    {
      char* lb = (char*)rows + (size_t)threadIdx.x * 16;
      *reinterpret_cast<float4*>(lb)         = v0;
      *reinterpret_cast<float4*>(lb + 8192)  = v1;
      *reinterpret_cast<float4*>(lb + 16384) = v2;
      *reinterpret_cast<float4*>(lb + 24576) = v3;
    }
    const int cA = ida, cB = idb;        // current batch ids
    LOADBATCH(bi + gridDim.x);           // issue NEXT batch loads now (T14)
    __syncthreads();                     // batch staged

    unsigned long long mA0 = __ballot(cA == cbase + 0);
    unsigned long long mA1 = __ballot(cA == cbase + 1);
    unsigned long long mA2 = __ballot(cA == cbase + 2);
    unsigned long long mA3 = __ballot(cA == cbase + 3);
    unsigned long long mB0 = __ballot(cB == cbase + 0);
    unsigned long long mB1 = __ballot(cB == cbase + 1);
    unsigned long long mB2 = __ballot(cB == cbase + 2);
    unsigned long long mB3 = __ballot(cB == cbase + 3);
    if (w == 0) { mA0 = 0; mB0 = 0; }    // cluster 0: stats unused

    POPLOOP(mA0, mA1, mA2, mA3, 0)
    POPLOOP(mB0, mB1, mB2, mB3, 64)
  }
#undef LOADBATCH
#undef POPLOOP

  // flush per-block f32 partials, coalesced (256 B per wave-store)
  float* pb = pws + (size_t)blockIdx.x * NPART;
  pb[(cbase + 0) * SDIM + lane] = s0;
  pb[(cbase + 1) * SDIM + lane] = s1;
  pb[(cbase + 2) * SDIM + lane] = s2;
  pb[(cbase + 3) * SDIM + lane] = s3;
  pb[KCL * SDIM + (cbase + 0) * SDIM + lane] = q0;
  pb[KCL * SDIM + (cbase + 1) * SDIM + lane] = q1;
  pb[KCL * SDIM + (cbase + 2) * SDIM + lane] = q2;
  pb[KCL * SDIM + (cbase + 3) * SDIM + lane] = q3;
  if (lane == 0) {
    pb[2 * KCL * SDIM + cbase + 0] = cn0;
    pb[2 * KCL * SDIM + cbase + 1] = cn1;
    pb[2 * KCL * SDIM + cbase + 2] = cn2;
    pb[2 * KCL * SDIM + cbase + 3] = cn3;
  }
}

// ---------------------------------------------------------------------------
// P2: deterministic tree reduce of f32 block partials -> f64 gstats[4128].
// Block handles 64 contiguous units; wave w sums blocks b=w,w+16,... with
// coalesced 256 B reads; fixed-order cross-wave combine. Deterministic.
// ---------------------------------------------------------------------------
__global__ __launch_bounds__(1024) void reduce_kernel(
    const float* __restrict__ pws, double* __restrict__ gstats, int nb)
{
  __shared__ double s_acc[16][64];
  const int lane = threadIdx.x & 63;
  const int w    = threadIdx.x >> 6;
  const int u    = blockIdx.x * 64 + lane;
  double acc = 0.0;
  if (u < NPART)
    for (int b = w; b < nb; b += 16)
      acc += (double)pws[(size_t)b * NPART + u];
  s_acc[w][lane] = acc;
  __syncthreads();
  if (w == 0 && u < NPART) {
    double t = 0.0;
#pragma unroll
    for (int j = 0; j < 16; ++j) t += s_acc[j][lane];
    gstats[u] = t;
  }
}

// ---------------------------------------------------------------------------
// P3: finalize means (f32, transposed [s][c]), t2, thr = 3*std, valid (f64)
// ---------------------------------------------------------------------------
__global__ __launch_bounds__(256) void finalize_kernel(
    const double* __restrict__ gstats, float* __restrict__ meansTf,
    double* __restrict__ t2, double* __restrict__ thr, int* __restrict__ validk)
{
  __shared__ double s_var[KCL], s_t2[KCL];
  if (threadIdx.x < KCL) { s_var[threadIdx.x] = 0.0; s_t2[threadIdx.x] = 0.0; }
  __syncthreads();
  const double* gsum = gstats;
  const double* gsq  = gstats + KCL * SDIM;
  const double* gcnt = gstats + 2 * KCL * SDIM;
  for (int i = threadIdx.x; i < KCL * SDIM; i += blockDim.x) {
    const int c = i / SDIM, s = i % SDIM;
    const double cnt  = gcnt[c];
    const double safe = fmax(cnt, 1.0);
    const double m    = gsum[i] / safe;
    const double var  = gsq[i] / safe - m * m;
    meansTf[s * KCL + c] = (float)m;
    unsafeAtomicAdd(&s_var[c], var);
    unsafeAtomicAdd(&s_t2[c], m * m);
  }
  __syncthreads();
  if (threadIdx.x < KCL) {
    const int c = threadIdx.x;
    thr[c]    = FACTOR_D * sqrt(fmax(s_var[c], 0.0));
    t2[c]     = s_t2[c];
    validk[c] = (c != 0 && gcnt[c] > 0.0) ? 1 : 0;
  }
}

// ---------------------------------------------------------------------------
// P4: single output pass. Matched rows: pass-through stores. Unmatched rows
// (sort_idx==0): wave computes dist to all clusters (lane=cluster), threshold
// mask, first-index-tie argmin, MAX_DIST override. f32 dot loop; f64 combine/
// compares to preserve np ordering semantics.
// ---------------------------------------------------------------------------
__global__ __launch_bounds__(256) void assign_kernel(
    const float* __restrict__ spikes, const int* __restrict__ sortidx,
    const int* __restrict__ matchidx, const float* __restrict__ distance,
    const float* __restrict__ meansTf, const double* __restrict__ t2g,
    const double* __restrict__ thrg, const int* __restrict__ validk,
    float* __restrict__ out, int n)
{
  __shared__ float  s_mT[SDIM][KCL];   // [s][c]
  __shared__ double s_t2[KCL], s_thr[KCL];
  __shared__ int    s_valid[KCL];
  for (int i = threadIdx.x; i < SDIM * KCL; i += blockDim.x)
    (&s_mT[0][0])[i] = meansTf[i];
  if (threadIdx.x < KCL) {
    s_t2[threadIdx.x]    = t2g[threadIdx.x];
    s_thr[threadIdx.x]   = thrg[threadIdx.x];
    s_valid[threadIdx.x] = validk[threadIdx.x];
  }
  __syncthreads();

  const int wave = threadIdx.x >> 6;
  const int lane = threadIdx.x & 63;
  const int c    = lane & 31;
  const int gw   = blockIdx.x * (blockDim.x >> 6) + wave;
  const int nw   = gridDim.x * (blockDim.x >> 6);

  const bool   act = (lane < KCL) && (s_valid[c] != 0);
  const double tc  = s_t2[c];
  const double thc = s_thr[c];

  long long chunk = (((long long)n + nw - 1) / nw + 63) & ~63LL;
  const long long start = (long long)gw * chunk;
  long long end = start + chunk; if (end > n) end = n;

  for (long long rbase = start; rbase < end; rbase += 64) {
    const long long rr = rbase + lane;
    int cv = 1;
    if (rr < end) {
      cv = sortidx[rr];
      if (cv != 0) {                       // matched: pass-through
        out[rr]            = (float)cv;
        out[n + rr]        = (float)matchidx[rr];
        out[2LL * n + rr]  = distance[rr];
      }
    }
    unsigned long long mask = __ballot(rr < end && cv == 0);
    while (mask) {
      const int b = __ffsll(mask) - 1;
      mask &= mask - 1;
      const long long r = rbase + b;

      const float xv = spikes[(size_t)r * SDIM + lane];
      float x2 = xv * xv;
#pragma unroll
      for (int off = 32; off > 0; off >>= 1) x2 += __shfl_xor(x2, off, 64);

      float dot = 0.0f;
#pragma unroll
      for (int s = 0; s < SDIM; ++s)
        dot = fmaf(__shfl(xv, s, 64), s_mT[s][c], dot);

      double dist; int idx = c;
      if (act) {
        const double d2 = (double)x2 - 2.0 * (double)dot + tc;
        dist = sqrt(fmax(d2, 1e-12));
        if (dist > thc) dist = (double)INFINITY;   // threshold mask
      } else {
        dist = (double)INFINITY;                   // invalid / duplicate lane
      }

#pragma unroll
      for (int off = 32; off > 0; off >>= 1) {     // min+argmin, first-idx tie
        const double od = __shfl_xor(dist, off, 64);
        const int    oi = __shfl_xor(idx, off, 64);
        if (od < dist || (od == dist && oi < idx)) { dist = od; idx = oi; }
      }

      if (lane == 0) {
        const int mz = (dist >= MAXDIST_TH) ? 0 : idx;
        out[r]            = (float)mz;
        out[n + r]        = MATCHED2_F;
        out[2LL * n + r]  = (float)dist;
      }
    }
  }
}

// ---------------------------------------------------------------------------
extern "C" void kernel_launch(void* const* d_in, const int* in_sizes, int n_in,
                              void* d_out, int out_size, void* d_ws, size_t ws_size,
                              hipStream_t stream) {
  const float* spikes   = (const float*)d_in[0];
  const int*   sortidx  = (const int*)d_in[1];
  const int*   matchidx = (const int*)d_in[2];
  const float* distance = (const float*)d_in[3];
  const int n = in_sizes[1];
  if (n <= 0) return;
  float* out = (float*)d_out;

  // ws layout: pws f32[SB*NPART] (~16.9 MB) | gstats f64[NPART]
  //            | meansTf f32[2048] | t2 f64[32] | thr f64[32] | validk i32[32]
  float*  pws     = (float*)d_ws;
  double* gstats  = (double*)((char*)d_ws +
                              (((size_t)SB * NPART * sizeof(float) + 15) & ~15ull));
  float*  meansTf = (float*)(gstats + NPART);
  double* t2      = (double*)(((size_t)(meansTf + KCL * SDIM) + 7) & ~7ull);
  double* thr     = t2 + KCL;
  int*    validk  = (int*)(thr + KCL);

  stats_kernel<<<SB, ST, 0, stream>>>(spikes, sortidx, pws, n);
  reduce_kernel<<<(NPART + 63) / 64, 1024, 0, stream>>>(pws, gstats, SB);
  finalize_kernel<<<1, 256, 0, stream>>>(gstats, meansTf, t2, thr, validk);
  assign_kernel<<<2048, 256, 0, stream>>>(spikes, sortidx, matchidx, distance,
                                          meansTf, t2, thr, validk, out, n);
}

// Round 7
// 141.214 us; speedup vs baseline: 5.5473x; 1.0057x over previous
//
#include <hip/hip_runtime.h>
#include <math.h>

// Problem constants (fixed by the reference problem instance).
#define SDIM 64               // spike waveform length S
#define KCL  32               // num_clusters K
#define NPART (KCL*SDIM*2 + KCL)  // 4128 partials: sum[K*S] ++ sq[K*S] ++ cnt[K]
#define FACTOR_D 3.0          // second_match_factor
#define MAXDIST_TH 1280.0     // MAX_DIST * S = 20 * 64
#define MATCHED2_F 2.0f       // SPIKE_MATCHED_2

#define SB 1024               // stats grid (4 blocks/CU, thread-limited)
#define ST 512                // stats threads = 8 waves
#define BATCH 128             // rows staged per batch (32 KB LDS)

// ---------------------------------------------------------------------------
// P1: owner-computes segment sums, zero atomics.
// Wave w owns clusters 4w..4w+3. Per batch: ballot one 64-bit mask per owned
// cluster, then pop 4 masks together per iteration (4 independent ds_reads in
// flight, predicated f32 accumulate).
// R7 fix: next-batch global loads are issued AFTER the staging barrier, so
// they stay in flight across the pop-loop and are drained only at the NEXT
// iteration's first barrier (hipcc emits vmcnt(0) before every s_barrier —
// issuing them before the barrier, as in R6, exposed the full HBM round-trip
// per batch between staging and compute).
// ---------------------------------------------------------------------------
__global__ __launch_bounds__(ST) void stats_kernel(
    const float* __restrict__ spikes, const int* __restrict__ sortidx,
    float* __restrict__ pws, int n)
{
  __shared__ float rows[BATCH * SDIM];   // 32 KB, linear [row][col]
  const int lane  = threadIdx.x & 63;
  const int w     = threadIdx.x >> 6;    // wave 0..7
  const int cbase = w * 4;               // first owned cluster

  float s0=0,s1=0,s2=0,s3=0;             // per-lane column sums, 4 clusters
  float q0=0,q1=0,q2=0,q3=0;             // column sums of squares
  float cn0=0,cn1=0,cn2=0,cn3=0;         // row counts (wave-uniform)

  const long long nbatch = ((long long)n + BATCH - 1) / BATCH;
  const size_t gmax = (size_t)n * SDIM * sizeof(float) - 16;

  float4 v0, v1, v2, v3;                 // staged-batch registers
  int ida, idb;                          // cluster ids rows 0..63 / 64..127

#define LOADBATCH(B)                                                         \
  {                                                                          \
    const long long bsafe = ((B) < nbatch) ? (B) : 0;                        \
    size_t g0 = (size_t)bsafe * BATCH * SDIM * sizeof(float) +               \
                (size_t)threadIdx.x * 16;                                    \
    size_t g1 = g0 + 8192, g2 = g0 + 16384, g3 = g0 + 24576;                 \
    if (g0 > gmax) g0 = gmax;                                                \
    if (g1 > gmax) g1 = gmax;                                                \
    if (g2 > gmax) g2 = gmax;                                                \
    if (g3 > gmax) g3 = gmax;                                                \
    v0 = *reinterpret_cast<const float4*>((const char*)spikes + g0);         \
    v1 = *reinterpret_cast<const float4*>((const char*)spikes + g1);         \
    v2 = *reinterpret_cast<const float4*>((const char*)spikes + g2);         \
    v3 = *reinterpret_cast<const float4*>((const char*)spikes + g3);         \
    const long long ra = bsafe * BATCH + lane, rb = ra + 64;                 \
    ida = ((B) < nbatch && ra < n) ? sortidx[ra] : -1;                       \
    idb = ((B) < nbatch && rb < n) ? sortidx[rb] : -1;                       \
  }

#define POPLOOP(m0,m1,m2,m3,BASE)                                            \
  while (m0 | m1 | m2 | m3) {                                                \
    const bool e0 = m0 != 0, e1 = m1 != 0, e2 = m2 != 0, e3 = m3 != 0;       \
    const int b0 = e0 ? __ffsll(m0) - 1 : 0;                                 \
    const int b1 = e1 ? __ffsll(m1) - 1 : 0;                                 \
    const int b2 = e2 ? __ffsll(m2) - 1 : 0;                                 \
    const int b3 = e3 ? __ffsll(m3) - 1 : 0;                                 \
    m0 &= m0 - 1; m1 &= m1 - 1; m2 &= m2 - 1; m3 &= m3 - 1;                  \
    const float x0 = rows[((BASE) + b0) * SDIM + lane];                      \
    const float x1 = rows[((BASE) + b1) * SDIM + lane];                      \
    const float x2 = rows[((BASE) + b2) * SDIM + lane];                      \
    const float x3 = rows[((BASE) + b3) * SDIM + lane];                      \
    const float y0 = e0 ? x0 : 0.0f, y1 = e1 ? x1 : 0.0f;                    \
    const float y2 = e2 ? x2 : 0.0f, y3 = e3 ? x3 : 0.0f;                    \
    s0 += y0; q0 = fmaf(y0, x0, q0); cn0 += e0 ? 1.0f : 0.0f;                \
    s1 += y1; q1 = fmaf(y1, x1, q1); cn1 += e1 ? 1.0f : 0.0f;                \
    s2 += y2; q2 = fmaf(y2, x2, q2); cn2 += e2 ? 1.0f : 0.0f;                \
    s3 += y3; q3 = fmaf(y3, x3, q3); cn3 += e3 ? 1.0f : 0.0f;                \
  }

  long long bi = blockIdx.x;
  LOADBATCH(bi);                         // prologue

  for (; bi < nbatch; bi += gridDim.x) {
    __syncthreads();                     // (1) prev batch fully consumed;
                                         //     drains in-flight next loads
    {
      char* lb = (char*)rows + (size_t)threadIdx.x * 16;
      *reinterpret_cast<float4*>(lb)         = v0;
      *reinterpret_cast<float4*>(lb + 8192)  = v1;
      *reinterpret_cast<float4*>(lb + 16384) = v2;
      *reinterpret_cast<float4*>(lb + 24576) = v3;
    }
    const int cA = ida, cB = idb;        // save ids before regs are reused
    __syncthreads();                     // (2) batch staged (lgkm drain only)

    LOADBATCH(bi + gridDim.x);           // issue NEXT loads: in flight across
                                         // the pop-loop, drained at next (1)

    unsigned long long mA0 = __ballot(cA == cbase + 0);
    unsigned long long mA1 = __ballot(cA == cbase + 1);
    unsigned long long mA2 = __ballot(cA == cbase + 2);
    unsigned long long mA3 = __ballot(cA == cbase + 3);
    unsigned long long mB0 = __ballot(cB == cbase + 0);
    unsigned long long mB1 = __ballot(cB == cbase + 1);
    unsigned long long mB2 = __ballot(cB == cbase + 2);
    unsigned long long mB3 = __ballot(cB == cbase + 3);
    if (w == 0) { mA0 = 0; mB0 = 0; }    // cluster 0: stats unused

    POPLOOP(mA0, mA1, mA2, mA3, 0)
    POPLOOP(mB0, mB1, mB2, mB3, 64)
  }
#undef LOADBATCH
#undef POPLOOP

  // flush per-block f32 partials, coalesced (256 B per wave-store)
  float* pb = pws + (size_t)blockIdx.x * NPART;
  pb[(cbase + 0) * SDIM + lane] = s0;
  pb[(cbase + 1) * SDIM + lane] = s1;
  pb[(cbase + 2) * SDIM + lane] = s2;
  pb[(cbase + 3) * SDIM + lane] = s3;
  pb[KCL * SDIM + (cbase + 0) * SDIM + lane] = q0;
  pb[KCL * SDIM + (cbase + 1) * SDIM + lane] = q1;
  pb[KCL * SDIM + (cbase + 2) * SDIM + lane] = q2;
  pb[KCL * SDIM + (cbase + 3) * SDIM + lane] = q3;
  if (lane == 0) {
    pb[2 * KCL * SDIM + cbase + 0] = cn0;
    pb[2 * KCL * SDIM + cbase + 1] = cn1;
    pb[2 * KCL * SDIM + cbase + 2] = cn2;
    pb[2 * KCL * SDIM + cbase + 3] = cn3;
  }
}

// ---------------------------------------------------------------------------
// P2: deterministic tree reduce of f32 block partials -> f64 gstats[4128].
// Block handles 64 contiguous units; wave w sums blocks b=w,w+16,... with
// coalesced 256 B reads; fixed-order cross-wave combine. Deterministic.
// ---------------------------------------------------------------------------
__global__ __launch_bounds__(1024) void reduce_kernel(
    const float* __restrict__ pws, double* __restrict__ gstats, int nb)
{
  __shared__ double s_acc[16][64];
  const int lane = threadIdx.x & 63;
  const int w    = threadIdx.x >> 6;
  const int u    = blockIdx.x * 64 + lane;
  double acc = 0.0;
  if (u < NPART)
    for (int b = w; b < nb; b += 16)
      acc += (double)pws[(size_t)b * NPART + u];
  s_acc[w][lane] = acc;
  __syncthreads();
  if (w == 0 && u < NPART) {
    double t = 0.0;
#pragma unroll
    for (int j = 0; j < 16; ++j) t += s_acc[j][lane];
    gstats[u] = t;
  }
}

// ---------------------------------------------------------------------------
// P3: finalize means (f32, transposed [s][c]), t2, thr = 3*std, valid (f64)
// ---------------------------------------------------------------------------
__global__ __launch_bounds__(256) void finalize_kernel(
    const double* __restrict__ gstats, float* __restrict__ meansTf,
    double* __restrict__ t2, double* __restrict__ thr, int* __restrict__ validk)
{
  __shared__ double s_var[KCL], s_t2[KCL];
  if (threadIdx.x < KCL) { s_var[threadIdx.x] = 0.0; s_t2[threadIdx.x] = 0.0; }
  __syncthreads();
  const double* gsum = gstats;
  const double* gsq  = gstats + KCL * SDIM;
  const double* gcnt = gstats + 2 * KCL * SDIM;
  for (int i = threadIdx.x; i < KCL * SDIM; i += blockDim.x) {
    const int c = i / SDIM, s = i % SDIM;
    const double cnt  = gcnt[c];
    const double safe = fmax(cnt, 1.0);
    const double m    = gsum[i] / safe;
    const double var  = gsq[i] / safe - m * m;
    meansTf[s * KCL + c] = (float)m;
    unsafeAtomicAdd(&s_var[c], var);
    unsafeAtomicAdd(&s_t2[c], m * m);
  }
  __syncthreads();
  if (threadIdx.x < KCL) {
    const int c = threadIdx.x;
    thr[c]    = FACTOR_D * sqrt(fmax(s_var[c], 0.0));
    t2[c]     = s_t2[c];
    validk[c] = (c != 0 && gcnt[c] > 0.0) ? 1 : 0;
  }
}

// ---------------------------------------------------------------------------
// P4: single output pass. Matched rows: pass-through stores. Unmatched rows
// (sort_idx==0): wave computes dist to all clusters (lane=cluster), threshold
// mask, first-index-tie argmin, MAX_DIST override. f32 dot loop; f64 combine/
// compares to preserve np ordering semantics.
// ---------------------------------------------------------------------------
__global__ __launch_bounds__(256) void assign_kernel(
    const float* __restrict__ spikes, const int* __restrict__ sortidx,
    const int* __restrict__ matchidx, const float* __restrict__ distance,
    const float* __restrict__ meansTf, const double* __restrict__ t2g,
    const double* __restrict__ thrg, const int* __restrict__ validk,
    float* __restrict__ out, int n)
{
  __shared__ float  s_mT[SDIM][KCL];   // [s][c]
  __shared__ double s_t2[KCL], s_thr[KCL];
  __shared__ int    s_valid[KCL];
  for (int i = threadIdx.x; i < SDIM * KCL; i += blockDim.x)
    (&s_mT[0][0])[i] = meansTf[i];
  if (threadIdx.x < KCL) {
    s_t2[threadIdx.x]    = t2g[threadIdx.x];
    s_thr[threadIdx.x]   = thrg[threadIdx.x];
    s_valid[threadIdx.x] = validk[threadIdx.x];
  }
  __syncthreads();

  const int wave = threadIdx.x >> 6;
  const int lane = threadIdx.x & 63;
  const int c    = lane & 31;
  const int gw   = blockIdx.x * (blockDim.x >> 6) + wave;
  const int nw   = gridDim.x * (blockDim.x >> 6);

  const bool   act = (lane < KCL) && (s_valid[c] != 0);
  const double tc  = s_t2[c];
  const double thc = s_thr[c];

  long long chunk = (((long long)n + nw - 1) / nw + 63) & ~63LL;
  const long long start = (long long)gw * chunk;
  long long end = start + chunk; if (end > n) end = n;

  for (long long rbase = start; rbase < end; rbase += 64) {
    const long long rr = rbase + lane;
    int cv = 1;
    if (rr < end) {
      cv = sortidx[rr];
      if (cv != 0) {                       // matched: pass-through
        out[rr]            = (float)cv;
        out[n + rr]        = (float)matchidx[rr];
        out[2LL * n + rr]  = distance[rr];
      }
    }
    unsigned long long mask = __ballot(rr < end && cv == 0);
    while (mask) {
      const int b = __ffsll(mask) - 1;
      mask &= mask - 1;
      const long long r = rbase + b;

      const float xv = spikes[(size_t)r * SDIM + lane];
      float x2 = xv * xv;
#pragma unroll
      for (int off = 32; off > 0; off >>= 1) x2 += __shfl_xor(x2, off, 64);

      float dot = 0.0f;
#pragma unroll
      for (int s = 0; s < SDIM; ++s)
        dot = fmaf(__shfl(xv, s, 64), s_mT[s][c], dot);

      double dist; int idx = c;
      if (act) {
        const double d2 = (double)x2 - 2.0 * (double)dot + tc;
        dist = sqrt(fmax(d2, 1e-12));
        if (dist > thc) dist = (double)INFINITY;   // threshold mask
      } else {
        dist = (double)INFINITY;                   // invalid / duplicate lane
      }

#pragma unroll
      for (int off = 32; off > 0; off >>= 1) {     // min+argmin, first-idx tie
        const double od = __shfl_xor(dist, off, 64);
        const int    oi = __shfl_xor(idx, off, 64);
        if (od < dist || (od == dist && oi < idx)) { dist = od; idx = oi; }
      }

      if (lane == 0) {
        const int mz = (dist >= MAXDIST_TH) ? 0 : idx;
        out[r]            = (float)mz;
        out[n + r]        = MATCHED2_F;
        out[2LL * n + r]  = (float)dist;
      }
    }
  }
}

// ---------------------------------------------------------------------------
extern "C" void kernel_launch(void* const* d_in, const int* in_sizes, int n_in,
                              void* d_out, int out_size, void* d_ws, size_t ws_size,
                              hipStream_t stream) {
  const float* spikes   = (const float*)d_in[0];
  const int*   sortidx  = (const int*)d_in[1];
  const int*   matchidx = (const int*)d_in[2];
  const float* distance = (const float*)d_in[3];
  const int n = in_sizes[1];
  if (n <= 0) return;
  float* out = (float*)d_out;

  // ws layout: pws f32[SB*NPART] (~16.9 MB) | gstats f64[NPART]
  //            | meansTf f32[2048] | t2 f64[32] | thr f64[32] | validk i32[32]
  float*  pws     = (float*)d_ws;
  double* gstats  = (double*)((char*)d_ws +
                              (((size_t)SB * NPART * sizeof(float) + 15) & ~15ull));
  float*  meansTf = (float*)(gstats + NPART);
  double* t2      = (double*)(((size_t)(meansTf + KCL * SDIM) + 7) & ~7ull);
  double* thr     = t2 + KCL;
  int*    validk  = (int*)(thr + KCL);

  stats_kernel<<<SB, ST, 0, stream>>>(spikes, sortidx, pws, n);
  reduce_kernel<<<(NPART + 63) / 64, 1024, 0, stream>>>(pws, gstats, SB);
  finalize_kernel<<<1, 256, 0, stream>>>(gstats, meansTf, t2, thr, validk);
  assign_kernel<<<2048, 256, 0, stream>>>(spikes, sortidx, matchidx, distance,
                                          meansTf, t2, thr, validk, out, n);
}